// Round 16
// baseline (252.559 us; speedup 1.0000x reference)
//
#include <hip/hip_runtime.h>
#include <math.h>

// Problem constants (fixed by setup_inputs)
#define NN   256   // N rows
#define CCH  512   // C features
#define MMM  64    // M slices
#define KPOS 8     // K positives
#define MARG 0.2f
#define MAGIC 0x5A17C0DEu

typedef _Float16 f16x8 __attribute__((ext_vector_type(8)));
typedef _Float16 f16x2 __attribute__((ext_vector_type(2)));
typedef float    f32x4 __attribute__((ext_vector_type(4)));
typedef unsigned long long u64;

// Packed fragment layout: P[m][rb][cb][lane]
#define FRAG(m, rb, cb) ((((size_t)(m) * 16 + (rb)) * 16 + (cb)) * 64)

// Workspace layout (bytes).
#define PH_OFF    ((size_t)0)
#define PH_BYTES  ((size_t)MMM * 16 * 16 * 64 * 16)   // 16,777,216
#define POS_OFF   (PH_OFF + PH_BYTES)
#define NEG_OFF   (POS_OFF + (size_t)NN * KPOS * 4)
#define S_OFF     (NEG_OFF + (size_t)NN * 4 * 8)
#define CNT_OFF   (S_OFF + (size_t)MMM * 4)
#define DONE_OFF  (CNT_OFF + (size_t)MMM * 4)
#define GO_OFF    (DONE_OFF + 64)
#define FLAGS_OFF (GO_OFF + 64)                       // 512 * 4 bytes

// async global->LDS, 16B per lane: LDS dest = wave-uniform base + lane*16
#define GLD_LDS16(gp, lp) __builtin_amdgcn_global_load_lds(                 \
    (const __attribute__((address_space(1))) void*)(gp),                    \
    (__attribute__((address_space(3))) void*)(lp), 16, 0, 0)

// fp32 sum of squares of 8 fp16 values, fixed order (deterministic).
static __device__ __forceinline__ float rowsq(f16x8 v, float acc) {
#if __has_builtin(__builtin_amdgcn_fdot2)
  f16x2 p0 = {v[0], v[1]}, p1 = {v[2], v[3]}, p2 = {v[4], v[5]}, p3 = {v[6], v[7]};
  acc = __builtin_amdgcn_fdot2(p0, p0, acc, false);
  acc = __builtin_amdgcn_fdot2(p1, p1, acc, false);
  acc = __builtin_amdgcn_fdot2(p2, p2, acc, false);
  acc = __builtin_amdgcn_fdot2(p3, p3, acc, false);
#else
  #pragma unroll
  for (int e = 0; e < 8; ++e) { float f = (float)v[e]; acc = fmaf(f, f, acc); }
#endif
  return acc;
}

#define MFMA16(d, a, b) d = __builtin_amdgcn_mfma_f32_16x16x32_f16(a, b, d, 0, 0, 0)

// ---------------------------------------------------------------------------
// Single fused kernel: [transpose 2 tiles/block + (block 0) kP + init]
//   -> flag/go device barrier (LOAD-polls + s_sleep; r11's RMW-poll was the
//      disaster; flags overwritten each launch -> poison/replay safe;
//      finalizer resets flags/go for the next replay)
//   -> [kB2: column-Gram + x2 + d_ap exchange + masked loss]  (r14 verbatim)
// Co-residency: 68.6 KB LDS + launch_bounds(512,4) => exactly 2 blocks/CU
// => capacity 512 == grid, so all blocks resident before anyone spins.
// ---------------------------------------------------------------------------
__global__ __launch_bounds__(512, 4) void kF(
    const float* __restrict__ f, f16x8* __restrict__ Ph,
    const int* __restrict__ label,
    int* __restrict__ pos_idx, u64* __restrict__ neg_mask,
    float* __restrict__ s_acc, unsigned int* __restrict__ c_acc,
    unsigned int* __restrict__ done3, unsigned int* __restrict__ go,
    unsigned int* __restrict__ flags, float* __restrict__ out) {
  __shared__ __align__(16) char smem[68608];

  int bid = blockIdx.x;                 // 512 blocks
  int t = threadIdx.x, lane = t & 63, w = t >> 6;   // 8 waves

  // ======== PHASE 1: transpose+pack, 2 tiles per block (1024 total) ========
  {
    unsigned int* S = (unsigned int*)smem;   // stride-17 + XOR layout, 34.9 KB
    #pragma unroll 1
    for (int u = 0; u < 2; ++u) {
      int tile = bid * 2 + u;
      int rb = tile >> 6, cb = (tile >> 2) & 15, mq = tile & 3;
      int s = t & 3, pg = t >> 2;       // pg 0..127
      #pragma unroll
      for (int it = 0; it < 4; ++it) {
        int p = it * 128 + pg;          // 0..511 (p = c_loc*16 + n_loc)
        int n_loc = p & 15, c_loc = p >> 4;
        const float4 v4 = *(const float4*)&f[((size_t)(rb * 16 + n_loc) * CCH
                                              + (cb * 32 + c_loc)) * MMM + mq * 16 + s * 4];
        unsigned int* W = &S[p * 17 + (4 * (s ^ (p >> 7)))];
        W[0] = (unsigned int)__builtin_bit_cast(unsigned short, (_Float16)v4.x);
        W[1] = (unsigned int)__builtin_bit_cast(unsigned short, (_Float16)v4.y);
        W[2] = (unsigned int)__builtin_bit_cast(unsigned short, (_Float16)v4.z);
        W[3] = (unsigned int)__builtin_bit_cast(unsigned short, (_Float16)v4.w);
      }
      __syncthreads();
      #pragma unroll
      for (int it = 0; it < 2; ++it) {
        int e = it * 512 + t;           // 0..1023
        int m_loc = e >> 6, l = e & 63;
        int m = mq * 16 + m_loc;
        int lg = l >> 4;
        int mcol = m_loc ^ (lg << 2);
        f16x8 vh;
        #pragma unroll
        for (int j = 0; j < 8; ++j) {
          unsigned int wv = S[((lg * 8 + j) * 16 + (l & 15)) * 17 + mcol];
          vh[j] = __builtin_bit_cast(_Float16, (unsigned short)(wv & 0xffffu));
        }
        Ph[FRAG(m, rb, cb) + l] = vh;
      }
      __syncthreads();                  // S reused by next tile
    }
  }

  // ======== Block 0 extras: kP (ballot) + accumulator init ========
  {
    u64* cm = (u64*)smem;               // [32 classes][4 words], 1 KB
    int lab = 0;
    if (bid == 0 && t < 256) {
      lab = label[t];
      #pragma unroll 1
      for (int c = 0; c < 32; ++c) {
        u64 b = __ballot(lab == c);
        if ((t & 63) == 0) cm[c * 4 + (t >> 6)] = b;
      }
    }
    __syncthreads();
    if (bid == 0 && t < 256) {
      int n = t;
      u64 pm0 = cm[lab*4+0], pm1 = cm[lab*4+1], pm2 = cm[lab*4+2], pm3 = cm[lab*4+3];
      const u64 P0 = pm0, P1 = pm1, P2 = pm2, P3 = pm3;
      u64 e0 = 0, e1 = 0, e2 = 0, e3 = 0;
      #pragma unroll
      for (int r = 0; r < KPOS; ++r) {  // first 8 of stable order (pos then neg)
        u64 q0 = pm0, q1 = pm1, q2 = pm2, q3 = pm3;
        if (!(pm0 | pm1 | pm2 | pm3)) { // P<8 fallback: promote negatives
          q0 = ~(P0 | e0); q1 = ~(P1 | e1); q2 = ~(P2 | e2); q3 = ~(P3 | e3);
        }
        int k;
        if (q0) k = __builtin_ctzll(q0);
        else if (q1) k = 64 + __builtin_ctzll(q1);
        else if (q2) k = 128 + __builtin_ctzll(q2);
        else if (q3) k = 192 + __builtin_ctzll(q3);
        else k = 0;
        pos_idx[n * KPOS + r] = k;
        u64 b = 1ull << (k & 63);
        if (k < 64)       { pm0 &= ~b; e0 |= b; }
        else if (k < 128) { pm1 &= ~b; e1 |= b; }
        else if (k < 192) { pm2 &= ~b; e2 |= b; }
        else              { pm3 &= ~b; e3 |= b; }
      }
      neg_mask[n*4+0] = ~e0; neg_mask[n*4+1] = ~e1;
      neg_mask[n*4+2] = ~e2; neg_mask[n*4+3] = ~e3;
    }
    if (bid == 0) {
      if (t < MMM) { s_acc[t] = 0.0f; c_acc[t] = 0u; }
      if (t == 0) *done3 = 0u;
    }
  }

  // ======== DEVICE BARRIER (store-flag / load-poll, no RMW spinning) ========
  __syncthreads();
  __threadfence();                      // release Ph writes (+ block-0 inits)
  if (t == 0)
    __hip_atomic_store(&flags[bid], MAGIC, __ATOMIC_RELEASE, __HIP_MEMORY_SCOPE_AGENT);
  if (bid == 0) {
    while (__hip_atomic_load(&flags[t], __ATOMIC_RELAXED, __HIP_MEMORY_SCOPE_AGENT) != MAGIC)
      __builtin_amdgcn_s_sleep(16);     // each thread owns one flag
    __syncthreads();
    __threadfence();                    // acquire everyone's Ph
    if (t == 0)
      __hip_atomic_store(go, MAGIC, __ATOMIC_RELEASE, __HIP_MEMORY_SCOPE_AGENT);
  } else {
    if (t == 0) {
      while (__hip_atomic_load(go, __ATOMIC_ACQUIRE, __HIP_MEMORY_SCOPE_AGENT) != MAGIC)
        __builtin_amdgcn_s_sleep(16);
    }
    __syncthreads();
    __threadfence();
  }

  // ======== PHASE 2: kB2 (r14 verbatim) ========
  char* LdsR = smem;                    // [4][16 KB] ring, 64 KB
  float* x2s = (float*)(smem + 65536);
  float (*dapl)[KPOS] = (float (*)[KPOS])(smem + 66560);
  float* red_s = (float*)(smem + 67584);
  unsigned int* red_c = (unsigned int*)(smem + 67616);
  unsigned int* lastFlag = (unsigned int*)(smem + 67648);

  int m = bid & 63;                     // XCD-aligned: m%8 == bid%8
  int tjj = bid >> 6;                   // 0..7: 32-column slice
  int n0 = tjj * 32;

  f32x4 acc[2][2];
  acc[0][0] = (f32x4){0,0,0,0}; acc[0][1] = (f32x4){0,0,0,0};
  acc[1][0] = (f32x4){0,0,0,0}; acc[1][1] = (f32x4){0,0,0,0};
  float xa0 = 0.0f, xa1 = 0.0f;

  #define STAGE2(nbuf, cbn)                                                  \
    { GLD_LDS16(Ph + FRAG(m, w * 2 + 0, (cbn)) + lane,                       \
                &LdsR[((nbuf) * 16 + w * 2 + 0) * 1024]);                    \
      GLD_LDS16(Ph + FRAG(m, w * 2 + 1, (cbn)) + lane,                       \
                &LdsR[((nbuf) * 16 + w * 2 + 1) * 1024]); }

  STAGE2(0, 0);
  STAGE2(1, 1);
  #pragma unroll 1
  for (int cb = 0; cb < 16; ++cb) {
    int buf = cb & 3;
    if (cb < 14) {
      STAGE2((cb + 2) & 3, cb + 2);
      asm volatile("s_waitcnt vmcnt(4)" ::: "memory");   // 2 stage-pairs fly
    } else if (cb == 14) {
      asm volatile("s_waitcnt vmcnt(2)" ::: "memory");
    } else {
      asm volatile("s_waitcnt vmcnt(0)" ::: "memory");
    }
    __builtin_amdgcn_s_barrier();       // raw barrier: no vmcnt drain
    __builtin_amdgcn_sched_barrier(0);  // pin reads below the barrier
    const f16x8* L = (const f16x8*)(&LdsR[buf * 16384]);
    f16x8 A0 = L[(w * 2 + 0) * 64 + lane];      // wave rows 32w..32w+15
    f16x8 A1 = L[(w * 2 + 1) * 64 + lane];      // wave rows 32w+16..
    f16x8 B0 = L[(tjj * 2 + 0) * 64 + lane];    // cols n0..n0+15
    f16x8 B1 = L[(tjj * 2 + 1) * 64 + lane];    // cols n0+16..
    MFMA16(acc[0][0], A0, B0); MFMA16(acc[0][1], A0, B1);
    MFMA16(acc[1][0], A1, B0); MFMA16(acc[1][1], A1, B1);
    xa0 = rowsq(A0, xa0);
    xa1 = rowsq(A1, xa1);
  }

  // x2: butterfly the 4 c-slice partials per row
  {
    float s0 = xa0; s0 += __shfl_xor(s0, 16, 64); s0 += __shfl_xor(s0, 32, 64);
    float s1 = xa1; s1 += __shfl_xor(s1, 16, 64); s1 += __shfl_xor(s1, 32, 64);
    if ((lane >> 4) == 0) {
      x2s[w * 32 + (lane & 15)] = s0;
      x2s[w * 32 + 16 + (lane & 15)] = s1;
    }
  }
  __syncthreads();

  // Pass A: d_ap exchange through LDS (each (pk,n) owned by exactly one lane)
  #pragma unroll
  for (int j = 0; j < 2; ++j) {
    int n = n0 + j * 16 + (lane & 15);
    #pragma unroll
    for (int p = 0; p < KPOS; ++p) {
      int pk = pos_idx[n * KPOS + p];
      if ((pk >> 5) == w && (lane >> 4) == ((pk >> 2) & 3)) {
        float g = 0.0f;
        int i1 = (pk >> 4) & 1;
        #pragma unroll
        for (int reg = 0; reg < 4; ++reg)
          if ((pk & 3) == reg) g = i1 ? acc[1][j][reg] : acc[0][j][reg];
        float z = x2s[pk] + x2s[n] - 2.0f * g;
        dapl[n - n0][p] = (pk == n) ? 0.0f : ((z > 0.0f) ? sqrtf(z) : 0.0f);
      }
    }
  }
  __syncthreads();

  // Pass B: masked triplet loss over (k = wave rows, n = cols)
  float ls = 0.0f; unsigned int lc = 0u;
  int kw = w >> 1;
  #pragma unroll
  for (int j = 0; j < 2; ++j) {
    int n = n0 + j * 16 + (lane & 15);
    float x2n = x2s[n];
    u64 nm = neg_mask[n * 4 + kw];
    float dv[KPOS];
    #pragma unroll
    for (int p = 0; p < KPOS; ++p) dv[p] = dapl[n - n0][p];
    #pragma unroll
    for (int i = 0; i < 2; ++i) {
      #pragma unroll
      for (int reg = 0; reg < 4; ++reg) {
        int k = 32 * w + i * 16 + (lane >> 4) * 4 + reg;
        float z = x2n + x2s[k] - 2.0f * acc[i][j][reg];
        float d = (z > 0.0f) ? sqrtf(z) : 0.0f;
        if ((nm >> (k & 63)) & 1ull) {
          #pragma unroll
          for (int p = 0; p < KPOS; ++p) {
            float tt = MARG + dv[p] - d;
            if (tt > 0.0f) { ls += tt; lc++; }
          }
        }
      }
    }
  }
  #pragma unroll
  for (int off = 32; off > 0; off >>= 1) {
    ls += __shfl_down(ls, off, 64);
    lc += __shfl_down(lc, off, 64);
  }
  if (lane == 0) { red_s[w] = ls; red_c[w] = lc; }
  __syncthreads();
  if (t == 0) {
    float S = 0.0f; unsigned int C = 0u;
    #pragma unroll
    for (int i = 0; i < 8; ++i) { S += red_s[i]; C += red_c[i]; }
    atomicAdd(&s_acc[m], S);
    atomicAdd(&c_acc[m], C);
    __threadfence();
    unsigned int prev = atomicAdd(done3, 1u);
    *lastFlag = (prev == 511u) ? 1u : 0u;
  }
  __syncthreads();
  if (*lastFlag) {                      // last block: finalize + reset barrier
    __threadfence();
    flags[t] = 0u;                      // reset for next replay
    if (t == 0) *go = 0u;
    if (t < 64) {
      float c  = (float)c_acc[t];
      float sm = s_acc[t];
      float mean = (c > 0.0f) ? (sm / c) : 0.0f;
      float csum = c;
      #pragma unroll
      for (int off = 32; off > 0; off >>= 1) {
        mean += __shfl_down(mean, off, 64);
        csum += __shfl_down(csum, off, 64);
      }
      if (t == 0) {
        out[0] = mean / 64.0f;
        // lm.size = M * N * K * (N-K) = 64*256*8*248 = 32,505,856
        out[1] = (csum / 64.0f) / 32505856.0f;
      }
    }
  }
}

extern "C" void kernel_launch(void* const* d_in, const int* in_sizes, int n_in,
                              void* d_out, int out_size, void* d_ws, size_t ws_size,
                              hipStream_t stream) {
  const float* feature = (const float*)d_in[0];
  const int*   label   = (const int*)d_in[1];
  char* w = (char*)d_ws;
  f16x8* Ph = (f16x8*)(w + PH_OFF);
  int*   pos = (int*)(w + POS_OFF);
  u64*   neg = (u64*)(w + NEG_OFF);
  float* s_acc = (float*)(w + S_OFF);
  unsigned int* c_acc = (unsigned int*)(w + CNT_OFF);
  unsigned int* done3 = (unsigned int*)(w + DONE_OFF);
  unsigned int* go    = (unsigned int*)(w + GO_OFF);
  unsigned int* flags = (unsigned int*)(w + FLAGS_OFF);
  float* out = (float*)d_out;

  kF<<<512, 512, 0, stream>>>(feature, Ph, label, pos, neg,
                              s_acc, c_acc, done3, go, flags, out);
}

// Round 17
// 46.654 us; speedup vs baseline: 5.4135x; 5.4135x over previous
//
#include <hip/hip_runtime.h>
#include <math.h>

// Problem constants (fixed by setup_inputs)
#define NN   256   // N rows
#define CCH  512   // C features
#define MMM  64    // M slices
#define KPOS 8     // K positives
#define MARG 0.2f

typedef _Float16 f16x8 __attribute__((ext_vector_type(8)));
typedef _Float16 f16x2 __attribute__((ext_vector_type(2)));
typedef float    f32x4 __attribute__((ext_vector_type(4)));

// Packed fragment layout (MFMA A and B operands read the same pattern):
// P[m][rb][cb][lane] : lane l holds X[m][rb*16 + (l&15)][cb*32 + (l>>4)*8 + j]
#define FRAG(m, rb, cb) ((((size_t)(m) * 16 + (rb)) * 16 + (cb)) * 64)

// Workspace layout (bytes).
#define PH_OFF   ((size_t)0)
#define PH_BYTES ((size_t)MMM * 16 * 16 * 64 * 16)   // 16,777,216
#define POS_OFF  (PH_OFF + PH_BYTES)
#define NEG_OFF  (POS_OFF + (size_t)NN * KPOS * 4)
#define S_OFF    (NEG_OFF + (size_t)NN * 4 * 8)
#define CNT_OFF  (S_OFF + (size_t)MMM * 4)
#define DONE_OFF (CNT_OFF + (size_t)MMM * 4)

// async global->LDS, 16B per lane: LDS dest = wave-uniform base + lane*16
#define GLD_LDS16(gp, lp) __builtin_amdgcn_global_load_lds(                 \
    (const __attribute__((address_space(1))) void*)(gp),                    \
    (__attribute__((address_space(3))) void*)(lp), 16, 0, 0)

// fp32 sum of squares of 8 fp16 values, fixed order (deterministic).
static __device__ __forceinline__ float rowsq(f16x8 v, float acc) {
#if __has_builtin(__builtin_amdgcn_fdot2)
  f16x2 p0 = {v[0], v[1]}, p1 = {v[2], v[3]}, p2 = {v[4], v[5]}, p3 = {v[6], v[7]};
  acc = __builtin_amdgcn_fdot2(p0, p0, acc, false);
  acc = __builtin_amdgcn_fdot2(p1, p1, acc, false);
  acc = __builtin_amdgcn_fdot2(p2, p2, acc, false);
  acc = __builtin_amdgcn_fdot2(p3, p3, acc, false);
#else
  #pragma unroll
  for (int e = 0; e < 8; ++e) { float f = (float)v[e]; acc = fmaf(f, f, acc); }
#endif
  return acc;
}

// ---------------------------------------------------------------------------
// Kernel TH: fused transpose + fp16 convert + fragment packing (r13 layout:
// stride 17 + XOR column swizzle, conflict-free). Block 1024 runs the kP
// ballot logic and zeroes accumulators + done counter.
// ---------------------------------------------------------------------------
__global__ __launch_bounds__(256) void kTH(const float* __restrict__ f,
                                           f16x8* __restrict__ Ph,
                                           const int* __restrict__ label,
                                           int* __restrict__ pos_idx,
                                           unsigned long long* __restrict__ neg_mask,
                                           float* __restrict__ s_acc,
                                           unsigned int* __restrict__ c_acc,
                                           unsigned int* __restrict__ done) {
  __shared__ unsigned int S[512 * 17 + 16];   // ~34.9 KB
  int bid = blockIdx.x;
  int t = threadIdx.x;

  if (bid >= 1024) {                     // ---- kP body (ballot version) ----
    unsigned long long* cm = (unsigned long long*)S;   // [32 classes][4 words]
    if (t < MMM) { s_acc[t] = 0.0f; c_acc[t] = 0u; }
    if (t == 0) *done = 0u;
    int lab = label[t];                  // t == k, 256 threads == NN
    int wv = t >> 6;
    #pragma unroll 1
    for (int c = 0; c < 32; ++c) {
      unsigned long long b = __ballot(lab == c);
      if ((t & 63) == 0) cm[c * 4 + wv] = b;
    }
    __syncthreads();
    int n = t;
    unsigned long long pm0 = cm[lab*4+0], pm1 = cm[lab*4+1],
                       pm2 = cm[lab*4+2], pm3 = cm[lab*4+3];
    const unsigned long long P0 = pm0, P1 = pm1, P2 = pm2, P3 = pm3;
    unsigned long long e0 = 0, e1 = 0, e2 = 0, e3 = 0;
    #pragma unroll
    for (int r = 0; r < 8; ++r) {        // first 8 of stable order (pos then neg)
      unsigned long long q0 = pm0, q1 = pm1, q2 = pm2, q3 = pm3;
      if (!(pm0 | pm1 | pm2 | pm3)) {    // P<8 fallback: promote negatives
        q0 = ~(P0 | e0); q1 = ~(P1 | e1); q2 = ~(P2 | e2); q3 = ~(P3 | e3);
      }
      int k;
      if (q0) k = __builtin_ctzll(q0);
      else if (q1) k = 64 + __builtin_ctzll(q1);
      else if (q2) k = 128 + __builtin_ctzll(q2);
      else if (q3) k = 192 + __builtin_ctzll(q3);
      else k = 0;
      pos_idx[n * KPOS + r] = k;
      unsigned long long b = 1ull << (k & 63);
      if (k < 64)       { pm0 &= ~b; e0 |= b; }
      else if (k < 128) { pm1 &= ~b; e1 |= b; }
      else if (k < 192) { pm2 &= ~b; e2 |= b; }
      else              { pm3 &= ~b; e3 |= b; }
    }
    neg_mask[n*4+0] = ~e0; neg_mask[n*4+1] = ~e1;
    neg_mask[n*4+2] = ~e2; neg_mask[n*4+3] = ~e3;
    return;
  }

  int rb = bid >> 6, cb = (bid >> 2) & 15, mq = bid & 3;
  // read phase: 512 (n,c) pairs x 16 m; each thread: 8 float4 loads
  int s = t & 3, pg = t >> 2;
  #pragma unroll
  for (int it = 0; it < 8; ++it) {
    int p = it * 64 + pg;               // 0..511 (p = c_loc*16 + n_loc)
    int n_loc = p & 15, c_loc = p >> 4;
    const float4 v4 = *(const float4*)&f[((size_t)(rb * 16 + n_loc) * CCH
                                          + (cb * 32 + c_loc)) * MMM + mq * 16 + s * 4];
    unsigned int* W = &S[p * 17 + (4 * (s ^ (p >> 7)))];
    W[0] = (unsigned int)__builtin_bit_cast(unsigned short, (_Float16)v4.x);
    W[1] = (unsigned int)__builtin_bit_cast(unsigned short, (_Float16)v4.y);
    W[2] = (unsigned int)__builtin_bit_cast(unsigned short, (_Float16)v4.z);
    W[3] = (unsigned int)__builtin_bit_cast(unsigned short, (_Float16)v4.w);
  }
  __syncthreads();
  // write phase: 16 m_loc x 64 lanes fragments, coalesced 16B stores
  #pragma unroll
  for (int it = 0; it < 4; ++it) {
    int e = it * 256 + t;
    int m_loc = e >> 6, l = e & 63;
    int m = mq * 16 + m_loc;
    int lg = l >> 4;
    int mcol = m_loc ^ (lg << 2);       // same XOR as writer
    f16x8 vh;
    #pragma unroll
    for (int j = 0; j < 8; ++j) {
      unsigned int w = S[((lg * 8 + j) * 16 + (l & 15)) * 17 + mcol];
      vh[j] = __builtin_bit_cast(_Float16, (unsigned short)(w & 0xffffu));
    }
    Ph[FRAG(m, rb, cb) + l] = vh;
  }
}

// ---------------------------------------------------------------------------
// Kernel B2 (2-node design): block = (m, 32-col slice). Stages ALL 256 rows
// chunk-wise (counted-vmcnt pipeline, NB=4 depth-2), computes the 256x32
// column-Gram via MFMA, x2 via in-loop fdot2 on the same A-fragments
// (fixed reduction order -> identical across blocks), exchanges the d_ap
// values through LDS (each (pk,n) entry owned by exactly one lane), then
// the masked triplet loss. Self-distance forced to exact 0. No kA2 node.
// ---------------------------------------------------------------------------
#define MFMA16(d, a, b) d = __builtin_amdgcn_mfma_f32_16x16x32_f16(a, b, d, 0, 0, 0)

__global__ __launch_bounds__(512, 4) void kB2(
    const f16x8* __restrict__ Ph, const int* __restrict__ pos_idx,
    const unsigned long long* __restrict__ neg_mask,
    float* __restrict__ s_acc, unsigned int* __restrict__ c_acc,
    unsigned int* __restrict__ done, float* __restrict__ out) {
  __shared__ __align__(16) char Lds[4][16 * 1024];   // 64 KB ring
  __shared__ float x2s[256];
  __shared__ float dapl[32][8];
  __shared__ float red_s[8];
  __shared__ unsigned int red_c[8];
  __shared__ unsigned int lastFlag;

  int bid = blockIdx.x;                 // 512 blocks
  int m = bid & 63;                     // XCD-aligned: m%8 == bid%8
  int tjj = bid >> 6;                   // 0..7: 32-column slice
  int t = threadIdx.x, lane = t & 63, w = t >> 6;   // 8 waves
  int n0 = tjj * 32;

  f32x4 acc[2][2];                      // [i: k-row16][j: n-col16]
  acc[0][0] = (f32x4){0,0,0,0}; acc[0][1] = (f32x4){0,0,0,0};
  acc[1][0] = (f32x4){0,0,0,0}; acc[1][1] = (f32x4){0,0,0,0};
  float xa0 = 0.0f, xa1 = 0.0f;         // x2 partials for rows 32w+(lane&15), +16

  // chunk = all 256 rows x 32 c = 16 frag-KB; wave w stages fb = 2w, 2w+1.
  #define STAGE2(nbuf, cbn)                                                  \
    { GLD_LDS16(Ph + FRAG(m, w * 2 + 0, (cbn)) + lane,                       \
                &Lds[nbuf][(w * 2 + 0) * 1024]);                             \
      GLD_LDS16(Ph + FRAG(m, w * 2 + 1, (cbn)) + lane,                       \
                &Lds[nbuf][(w * 2 + 1) * 1024]); }

  STAGE2(0, 0);
  STAGE2(1, 1);
  #pragma unroll 1
  for (int cb = 0; cb < 16; ++cb) {
    int buf = cb & 3;
    if (cb < 14) {
      STAGE2((cb + 2) & 3, cb + 2);
      asm volatile("s_waitcnt vmcnt(4)" ::: "memory");   // 2 stage-pairs fly
    } else if (cb == 14) {
      asm volatile("s_waitcnt vmcnt(2)" ::: "memory");
    } else {
      asm volatile("s_waitcnt vmcnt(0)" ::: "memory");
    }
    __builtin_amdgcn_s_barrier();       // raw barrier: no vmcnt drain
    __builtin_amdgcn_sched_barrier(0);  // pin reads below the barrier
    const f16x8* L = (const f16x8*)(Lds[buf]);
    f16x8 A0 = L[(w * 2 + 0) * 64 + lane];      // wave rows 32w..32w+15
    f16x8 A1 = L[(w * 2 + 1) * 64 + lane];      // wave rows 32w+16..
    f16x8 B0 = L[(tjj * 2 + 0) * 64 + lane];    // cols n0..n0+15
    f16x8 B1 = L[(tjj * 2 + 1) * 64 + lane];    // cols n0+16..
    MFMA16(acc[0][0], A0, B0); MFMA16(acc[0][1], A0, B1);
    MFMA16(acc[1][0], A1, B0); MFMA16(acc[1][1], A1, B1);
    xa0 = rowsq(A0, xa0);               // x2 partial, c-slice (lane>>4)*8
    xa1 = rowsq(A1, xa1);
  }

  // x2: butterfly the 4 c-slice partials per row (lanes l, l^16, l^32, l^48)
  {
    float s0 = xa0; s0 += __shfl_xor(s0, 16, 64); s0 += __shfl_xor(s0, 32, 64);
    float s1 = xa1; s1 += __shfl_xor(s1, 16, 64); s1 += __shfl_xor(s1, 32, 64);
    if ((lane >> 4) == 0) {
      x2s[w * 32 + (lane & 15)] = s0;
      x2s[w * 32 + 16 + (lane & 15)] = s1;
    }
  }
  __syncthreads();

  // Pass A: d_ap exchange. Entry (pk, n) lives in wave pk>>5, lane with
  // lane&15 == n&15 and lane>>4 == (pk&15)>>2, at acc[(pk>>4)&1][j][pk&3].
  #pragma unroll
  for (int j = 0; j < 2; ++j) {
    int n = n0 + j * 16 + (lane & 15);
    #pragma unroll
    for (int p = 0; p < 8; ++p) {
      int pk = pos_idx[n * KPOS + p];
      if ((pk >> 5) == w && (lane >> 4) == ((pk >> 2) & 3)) {
        float g = 0.0f;
        int i1 = (pk >> 4) & 1;
        #pragma unroll
        for (int reg = 0; reg < 4; ++reg)
          if ((pk & 3) == reg) g = i1 ? acc[1][j][reg] : acc[0][j][reg];
        float z = x2s[pk] + x2s[n] - 2.0f * g;
        dapl[n - n0][p] = (pk == n) ? 0.0f : ((z > 0.0f) ? sqrtf(z) : 0.0f);
      }
    }
  }
  __syncthreads();

  // Pass B: masked triplet loss over this block's (k = wave rows, n = cols).
  float ls = 0.0f; unsigned int lc = 0u;
  int kw = w >> 1;                      // neg_mask word for k in [32w, 32w+32)
  #pragma unroll
  for (int j = 0; j < 2; ++j) {
    int n = n0 + j * 16 + (lane & 15);
    float x2n = x2s[n];
    unsigned long long nm = neg_mask[n * 4 + kw];
    float dv[8];
    #pragma unroll
    for (int p = 0; p < 8; ++p) dv[p] = dapl[n - n0][p];
    #pragma unroll
    for (int i = 0; i < 2; ++i) {
      #pragma unroll
      for (int reg = 0; reg < 4; ++reg) {
        int k = 32 * w + i * 16 + (lane >> 4) * 4 + reg;
        float z = x2n + x2s[k] - 2.0f * acc[i][j][reg];
        float d = (z > 0.0f) ? sqrtf(z) : 0.0f;
        if ((nm >> (k & 63)) & 1ull) {
          #pragma unroll
          for (int p = 0; p < 8; ++p) {
            float tt = MARG + dv[p] - d;
            if (tt > 0.0f) { ls += tt; lc++; }
          }
        }
      }
    }
  }
  #pragma unroll
  for (int off = 32; off > 0; off >>= 1) {
    ls += __shfl_down(ls, off, 64);
    lc += __shfl_down(lc, off, 64);
  }
  if (lane == 0) { red_s[w] = ls; red_c[w] = lc; }
  __syncthreads();
  if (t == 0) {
    float S = 0.0f; unsigned int C = 0u;
    #pragma unroll
    for (int i = 0; i < 8; ++i) { S += red_s[i]; C += red_c[i]; }
    atomicAdd(&s_acc[m], S);
    atomicAdd(&c_acc[m], C);
    __threadfence();
    unsigned int prev = atomicAdd(done, 1u);
    lastFlag = (prev == 511u) ? 1u : 0u;
  }
  __syncthreads();
  if (lastFlag && t < 64) {             // last block finalizes (fold of kC)
    __threadfence();
    float c  = (float)c_acc[t];
    float sm = s_acc[t];
    float mean = (c > 0.0f) ? (sm / c) : 0.0f;
    float csum = c;
    #pragma unroll
    for (int off = 32; off > 0; off >>= 1) {
      mean += __shfl_down(mean, off, 64);
      csum += __shfl_down(csum, off, 64);
    }
    if (t == 0) {
      out[0] = mean / 64.0f;
      // lm.size = M * N * K * (N-K) = 64*256*8*248 = 32,505,856
      out[1] = (csum / 64.0f) / 32505856.0f;
    }
  }
}

extern "C" void kernel_launch(void* const* d_in, const int* in_sizes, int n_in,
                              void* d_out, int out_size, void* d_ws, size_t ws_size,
                              hipStream_t stream) {
  const float* feature = (const float*)d_in[0];
  const int*   label   = (const int*)d_in[1];
  char* w = (char*)d_ws;
  f16x8* Ph = (f16x8*)(w + PH_OFF);
  int*   pos = (int*)(w + POS_OFF);
  unsigned long long* neg = (unsigned long long*)(w + NEG_OFF);
  float* s_acc = (float*)(w + S_OFF);
  unsigned int* c_acc = (unsigned int*)(w + CNT_OFF);
  unsigned int* done  = (unsigned int*)(w + DONE_OFF);
  float* out = (float*)d_out;

  kTH<<<1025, 256, 0, stream>>>(feature, Ph, label, pos, neg, s_acc, c_acc, done);
  kB2<<<512,  512, 0, stream>>>(Ph, pos, neg, s_acc, c_acc, done, out);
}